// Round 15
// baseline (875.127 us; speedup 1.0000x reference)
//
#include <hip/hip_runtime.h>
#include <hip/hip_bf16.h>

#define DI __device__ __forceinline__

typedef float f32x4 __attribute__((ext_vector_type(4)));
typedef __bf16 bf16x8 __attribute__((ext_vector_type(8)));
using bf16_t = __hip_bfloat16;
using ushort_t = unsigned short;

// ---------------- async global->LDS (16B per lane) ----------------
DI void gload_lds16(const void* g, void* l) {
  __builtin_amdgcn_global_load_lds(
      (const __attribute__((address_space(1))) void*)g,
      (__attribute__((address_space(3))) void*)l, 16, 0, 0);
}

DI float rcpf(float x) { return __builtin_amdgcn_rcpf(x); }

DI float us2f(ushort_t u) {
  bf16_t h;
  *reinterpret_cast<ushort_t*>(&h) = u;
  return __bfloat162float(h);
}

// ---------------- 20-way weighted activation mixture ----------------
DI float act_mix(float x, const float* aw, float lam) {
  const float ax  = fabsf(x);
  const float en  = __expf(-ax);        // e^{-|x|} in (0,1]
  const float en2 = en * en;            // e^{-2|x|}
  const float i1  = rcpf(1.0f + en);
  const float sig = (x >= 0.0f) ? i1 : en * i1;            // sigmoid
  const float th  = copysignf((1.0f - en2) * rcpf(1.0f + en2), x); // tanh
  const float l1p = __logf(1.0f + en);
  const float sp  = fmaxf(x, 0.0f) + l1p;                  // softplus
  const float lsg = fminf(x, 0.0f) - l1p;                  // logsigmoid
  const float q   = ((x >= 0.0f) ? en2 : 1.0f) * (i1 * i1);// e^{-2*softplus}
  const float mish = x * (1.0f - q) * rcpf(1.0f + q);
  // gelu exact via A&S 7.1.26 erf approx (|err|<=1.5e-7)
  const float u  = 0.7071067811865476f * x;
  const float au = fabsf(u);
  const float t  = rcpf(1.0f + 0.3275911f * au);
  float poly = fmaf(t, 1.061405429f, -1.453152027f);
  poly = fmaf(t, poly, 1.421413741f);
  poly = fmaf(t, poly, -0.284496736f);
  poly = fmaf(t, poly, 0.254829592f);
  poly *= t;
  const float erfa = 1.0f - poly * __expf(-u * u);
  const float gelu = 0.5f * x * (1.0f + copysignf(erfa, x));
  const float em1  = en - 1.0f;                            // e^x-1 for x<=0
  const float elu  = (x > 0.0f) ? x : em1;
  const float selu = (x > 0.0f) ? 1.0507009873554805f * x : 1.7580993408473766f * em1;
  const float relu = fmaxf(x, 0.0f);
  const float t6   = fminf(fmaxf(x + 3.0f, 0.0f), 6.0f) * 0.16666666666666666f;
  const float ssh  = (x > lam) ? (x - lam) : ((x < -lam) ? (x + lam) : 0.0f);
  const float hsh  = (ax > lam) ? x : 0.0f;
  const float htan = fminf(fmaxf(x, -1.0f), 1.0f);
  const float lky  = (x >= 0.0f) ? x : 0.01f * x;
  const float ssn  = x * rcpf(1.0f + ax);
  float r = aw[0] * ssh;
  r = fmaf(aw[1],  relu,   r);
  r = fmaf(aw[2],  x,      r);
  r = fmaf(aw[3],  gelu,   r);
  r = fmaf(aw[4],  elu,    r);
  r = fmaf(aw[5],  hsh,    r);
  r = fmaf(aw[6],  htan,   r);
  r = fmaf(aw[7],  x * t6, r);
  r = fmaf(aw[8],  selu,   r);
  r = fmaf(aw[9],  elu,    r);   // celu(alpha=1) == elu
  r = fmaf(aw[10], lky,    r);
  r = fmaf(aw[11], lsg,    r);
  r = fmaf(aw[12], x - th, r);
  r = fmaf(aw[13], ssn,    r);
  r = fmaf(aw[14], sp,     r);
  r = fmaf(aw[15], th,     r);
  r = fmaf(aw[16], sig,    r);
  r = fmaf(aw[17], t6,     r);
  r = fmaf(aw[18], x * sig, r);
  r = fmaf(aw[19], mish,   r);
  return r;
}

// ---------------- fused prep: hi/lo splits of W (+W^T); x -> bf16 ----------
__global__ void k_prep(const float* __restrict__ W, const float* __restrict__ x,
                       bf16_t* __restrict__ Whi, bf16_t* __restrict__ Wlo,
                       bf16_t* __restrict__ Wth, bf16_t* __restrict__ Wtl,
                       bf16_t* __restrict__ xb) {
  int i = blockIdx.x * 256 + threadIdx.x;
  if (i < 512 * 1024) {
    float w = W[i];
    bf16_t h = __float2bfloat16(w);
    bf16_t l = __float2bfloat16(w - __bfloat162float(h));
    Whi[i] = h; Wlo[i] = l;
    int n = i >> 10, hc = i & 1023;
    Wth[hc * 512 + n] = h; Wtl[hc * 512 + n] = l;
  }
  int j = i - 512 * 1024;
  if (j >= 0 && j < 4096 * 512) xb[j] = __float2bfloat16(x[j]);
}

// ---------------- fused L-chain: ONE launch, software grid barrier ---------
// Replaces 9 k_sqm launches + k_setup (round 14: ~50-60us of launch gaps and
// 1-block/CU ramps). 256 blocks x 256 threads; launch_bounds(256,1) + 32KB LDS
// -> max co-resident >= 1024 >= grid for ANY block distribution: the spin
// barrier cannot deadlock. NOT hipLaunchCooperativeKernel (round 13: silently
// rejected). Barrier: flags[bid]=g (256 distinct addrs, no atomic contention);
// block 0's 256 threads poll one flag each, then publish gen=g; others spin
// on gen. Device-scope (AGENT) atomics handle cross-XCD L2 visibility.
// Phase math = round-14 k_sqm verbatim (absmax must stay exactly 0.015625).
__global__ __launch_bounds__(256, 1) void k_Lchain(
    const bf16_t* __restrict__ Whi, const bf16_t* __restrict__ Wlo,
    bf16_t* __restrict__ H0, bf16_t* __restrict__ L0,
    bf16_t* __restrict__ H1, bf16_t* __restrict__ L1,
    float* __restrict__ A0f, float* __restrict__ pb,   // 8 x 256 partials
    float* __restrict__ numP, float* __restrict__ denP,
    const float* __restrict__ alpha, const float* __restrict__ beta,
    float* __restrict__ params, int* flags, int* gen) {
  __shared__ __align__(16) ushort_t Ah[2][2048], Al[2][2048],
                                    Bh[2][2048], Bl[2][2048];
  __shared__ float red[4], redd[4];
  const int tid = threadIdx.x, lane = tid & 63, wave = tid >> 6;
  const int wm = wave >> 1, wn = wave & 1;
  const int bid = blockIdx.x;                    // 0..255
  const int i0 = (bid & 15) * 32, j0 = (bid >> 4) * 32;
  const int r16 = lane & 15, kg = lane >> 4;
  const int row = tid >> 3;
  const int srcc = (((tid & 7) ^ (row & 7)) << 3);
  const int ldst = tid * 8;

  auto gbar = [&](int g) {
    __syncthreads();
    __threadfence();                                        // release my writes
    if (tid == 0)
      __hip_atomic_store(&flags[bid], g, __ATOMIC_RELEASE, __HIP_MEMORY_SCOPE_AGENT);
    if (bid == 0) {
      while (__hip_atomic_load(&flags[tid], __ATOMIC_ACQUIRE,
                               __HIP_MEMORY_SCOPE_AGENT) < g) {}
      __syncthreads();
      if (tid == 0)
        __hip_atomic_store(gen, g, __ATOMIC_RELEASE, __HIP_MEMORY_SCOPE_AGENT);
    } else {
      if (tid == 0)
        while (__hip_atomic_load(gen, __ATOMIC_ACQUIRE,
                                 __HIP_MEMORY_SCOPE_AGENT) < g) {}
      __syncthreads();
    }
    __threadfence();                                        // acquire side
  };

  // one squaring phase: C = s*(X·X^T) via hi/lo 3-term MFMA, counted-vmcnt
  // pipeline (round-14 k_sqm body). first: s=1, also writes Cf. dot: reads
  // Cf for tr(A0*C) and tr(C) partials instead of writing C.
  auto phase = [&](const bf16_t* Xhi, const bf16_t* Xlo, int KDIM,
                   bf16_t* Chi, bf16_t* Clo, bool first, bool dot,
                   const float* pin, float* pout) {
    float s = 1.0f;
    if (!first) {
      float v = pin[tid];
      for (int off = 32; off; off >>= 1) v += __shfl_down(v, off, 64);
      if ((tid & 63) == 0) red[tid >> 6] = v;
      __syncthreads();
      s = 1.0f / (red[0] + red[1] + red[2] + red[3]);
      __syncthreads();
    }
    const long abase = (long)(i0 + row) * KDIM + srcc;
    const long bbase = (long)(j0 + row) * KDIM + srcc;
    auto stage = [&](int buf, int kt) {          // 4 gload_lds / thread
      gload_lds16(Xhi + abase + kt, &Ah[buf][ldst]);
      gload_lds16(Xlo + abase + kt, &Al[buf][ldst]);
      gload_lds16(Xhi + bbase + kt, &Bh[buf][ldst]);
      gload_lds16(Xlo + bbase + kt, &Bl[buf][ldst]);
    };
    f32x4 acc = {};
    const int NT = KDIM / 64;
    auto compute = [&](int b) {
      const int ra = wm * 16 + r16, rb = wn * 16 + r16;
#pragma unroll
      for (int kk = 0; kk < 64; kk += 32) {
        int oa = ra * 64 + ((kk + kg * 8) ^ ((ra & 7) * 8));
        int ob = rb * 64 + ((kk + kg * 8) ^ ((rb & 7) * 8));
        bf16x8 ah = *(const bf16x8*)&Ah[b][oa];
        bf16x8 al = *(const bf16x8*)&Al[b][oa];
        bf16x8 bh = *(const bf16x8*)&Bh[b][ob];
        bf16x8 bl = *(const bf16x8*)&Bl[b][ob];
        acc = __builtin_amdgcn_mfma_f32_16x16x32_bf16(ah, bh, acc, 0, 0, 0);
        acc = __builtin_amdgcn_mfma_f32_16x16x32_bf16(ah, bl, acc, 0, 0, 0);
        acc = __builtin_amdgcn_mfma_f32_16x16x32_bf16(al, bh, acc, 0, 0, 0);
      }
    };

    stage(0, 0);
    stage(1, 64);
    asm volatile("s_waitcnt vmcnt(4)" ::: "memory");
    __builtin_amdgcn_s_barrier();
    __builtin_amdgcn_sched_barrier(0);
    for (int t = 0; t < NT; ++t) {
      compute(t & 1);
      if (t == NT - 1) break;
      asm volatile("s_waitcnt lgkmcnt(0)" ::: "memory");
      __builtin_amdgcn_sched_barrier(0);
      __builtin_amdgcn_s_barrier();
      if (t + 2 < NT) {
        stage(t & 1, (t + 2) * 64);
        asm volatile("s_waitcnt vmcnt(4)" ::: "memory");
      } else {
        asm volatile("s_waitcnt vmcnt(0)" ::: "memory");
      }
      __builtin_amdgcn_s_barrier();
      __builtin_amdgcn_sched_barrier(0);
    }
    __builtin_amdgcn_sched_barrier(0);

    float fro = 0.0f, dvp = 0.0f;
#pragma unroll
    for (int r = 0; r < 4; ++r) {
      float c = acc[r] * s;
      int orow = i0 + wm * 16 + (lane >> 4) * 4 + r;
      int ocol = j0 + wn * 16 + r16;
      int idx = orow * 512 + ocol;
      if (dot) {
        fro = fmaf(A0f[idx], c, fro);     // tr(A0 * C) partial
        if (orow == ocol) dvp += c;       // tr(C) partial
      } else {
        bf16_t h = __float2bfloat16(c);
        Chi[idx] = h;
        Clo[idx] = __float2bfloat16(c - __bfloat162float(h));
        if (first) A0f[idx] = c;
        fro = fmaf(c, c, fro);
      }
    }
    for (int off = 32; off; off >>= 1) {
      fro += __shfl_down(fro, off, 64);
      if (dot) dvp += __shfl_down(dvp, off, 64);
    }
    if ((tid & 63) == 0) { red[tid >> 6] = fro; if (dot) redd[tid >> 6] = dvp; }
    __syncthreads();
    if (tid == 0) {
      if (dot) {
        numP[bid] = red[0] + red[1] + red[2] + red[3];
        denP[bid] = redd[0] + redd[1] + redd[2] + redd[3];
      } else {
        pout[bid] = red[0] + red[1] + red[2] + red[3];
      }
    }
  };

  // A0 = W*W^T (K=1024), 7 normalized squarings, DOT-squaring (= A_hat^256)
  phase(Whi, Wlo, 1024, H0, L0, true, false, nullptr, pb);
  gbar(1);
  bf16_t* Hs[2] = {H0, H1};
  bf16_t* Ls[2] = {L0, L1};
  int pp = 0;
  for (int k = 0; k < 7; ++k) {
    phase(Hs[pp], Ls[pp], 512, Hs[pp ^ 1], Ls[pp ^ 1], false, false,
          pb + k * 256, pb + (k + 1) * 256);
    gbar(k + 2);
    pp ^= 1;
  }
  phase(Hs[pp], Ls[pp], 512, nullptr, nullptr, false, true,
        pb + 7 * 256, nullptr);
  gbar(9);

  // ---- k_setup body, block 0 only ----
  if (bid != 0) return;
  {
    __shared__ float redn2[4], redd2[4];
    __shared__ float Lsh;
    float nv = numP[tid], dv = denP[tid];
    for (int off = 32; off; off >>= 1) {
      nv += __shfl_down(nv, off, 64);
      dv += __shfl_down(dv, off, 64);
    }
    if ((tid & 63) == 0) { redn2[tid >> 6] = nv; redd2[tid >> 6] = dv; }
    __syncthreads();
    if (tid == 0)
      Lsh = (redn2[0] + redn2[1] + redn2[2] + redn2[3]) /
            (redd2[0] + redd2[1] + redd2[2] + redd2[3]);
    __syncthreads();
    const int t = tid;
    if (t >= 10) return;
    float L = Lsh;
    float invL = 1.0f / L;
    float lam = 0.001f * invL;
    const float* a = alpha + t * 20;
    float mx = a[0];
    for (int k = 1; k < 20; ++k) mx = fmaxf(mx, a[k]);
    float e[20], ssum = 0.0f;
    for (int k = 0; k < 20; ++k) { e[k] = expf(a[k] - mx); ssum += e[k]; }
    float inv = 1.0f / ssum;
    float* P = params + t * 32;
    for (int k = 0; k < 20; ++k) P[k] = e[k] * inv;
    float b0 = beta[t * 2], b1 = beta[t * 2 + 1];
    float bm = fmaxf(b0, b1);
    float eb0 = expf(b0 - bm), eb1 = expf(b1 - bm);
    float bw0 = eb0 / (eb0 + eb1);
    P[20] = ((float)(t + 1) / (float)(t + 4)) * bw0;  // c_{i+1} * bw0_i
    P[21] = invL;
    P[22] = lam;
    P[23] = L;
  }
}

// ---------------- merged: G = W^T W  AND  xWs + fused iter 0 ----------------
__global__ __launch_bounds__(256, 4) void k_gx(
    const bf16_t* __restrict__ xb, const bf16_t* __restrict__ Wth,
    const bf16_t* __restrict__ Wtl, const float* __restrict__ prm,
    bf16_t* __restrict__ Gm, bf16_t* __restrict__ xWs,
    bf16_t* __restrict__ zB, bf16_t* __restrict__ zaux1) {
  __shared__ __align__(16) ushort_t smem[16384];   // 32 KB
  const int tid = threadIdx.x, lane = tid & 63, wave = tid >> 6;
  const int wm = wave >> 1, wn = wave & 1;
  const int r16 = lane & 15, kg = lane >> 4;

  if ((int)blockIdx.x >= 1024) {
    // ---------- G part: 1024 blocks of 32x32, hi/lo 3-term ----------
    const int gb = blockIdx.x - 1024;
    const int i0 = (gb & 31) * 32, j0 = (gb >> 5) * 32;
    ushort_t* Ah = smem;            // [2][2048] each
    ushort_t* Al = smem + 4096;
    ushort_t* Bh = smem + 8192;
    ushort_t* Bl = smem + 12288;
    const int row = tid >> 3;
    const int srcc = (((tid & 7) ^ (row & 7)) << 3);
    const long abase = (long)(i0 + row) * 512 + srcc;
    const long bbase = (long)(j0 + row) * 512 + srcc;
    const int ldst = tid * 8;
    auto stg = [&](int buf, int kt) {
      gload_lds16(Wth + abase + kt, &Ah[buf * 2048 + ldst]);
      gload_lds16(Wtl + abase + kt, &Al[buf * 2048 + ldst]);
      gload_lds16(Wth + bbase + kt, &Bh[buf * 2048 + ldst]);
      gload_lds16(Wtl + bbase + kt, &Bl[buf * 2048 + ldst]);
    };
    f32x4 acc = {};
    stg(0, 0);
    __syncthreads();
    for (int t = 0; t < 8; ++t) {
      if (t + 1 < 8) stg((t + 1) & 1, (t + 1) * 64);
      const int b = t & 1;
      const int ra = wm * 16 + r16, rb = wn * 16 + r16;
#pragma unroll
      for (int kk = 0; kk < 64; kk += 32) {
        int oa = b * 2048 + ra * 64 + ((kk + kg * 8) ^ ((ra & 7) * 8));
        int ob = b * 2048 + rb * 64 + ((kk + kg * 8) ^ ((rb & 7) * 8));
        bf16x8 ah = *(const bf16x8*)&Ah[oa];
        bf16x8 al = *(const bf16x8*)&Al[oa];
        bf16x8 bh = *(const bf16x8*)&Bh[ob];
        bf16x8 bl = *(const bf16x8*)&Bl[ob];
        acc = __builtin_amdgcn_mfma_f32_16x16x32_bf16(ah, bh, acc, 0, 0, 0);
        acc = __builtin_amdgcn_mfma_f32_16x16x32_bf16(ah, bl, acc, 0, 0, 0);
        acc = __builtin_amdgcn_mfma_f32_16x16x32_bf16(al, bh, acc, 0, 0, 0);
      }
      __syncthreads();
    }
#pragma unroll
    for (int r = 0; r < 4; ++r) {
      int orow = i0 + wm * 16 + (lane >> 4) * 4 + r;
      int ocol = j0 + wn * 16 + r16;
      Gm[orow * 1024 + ocol] = __float2bfloat16(acc[r]);
    }
    return;
  }

  // ---------- xw part: 1024 blocks, counted-vmcnt pipeline ----------
  const int bid = blockIdx.x;
  const int swz = (bid & 7) * 128 + (bid >> 3);   // XCD swizzle
  const int m0 = (swz >> 4) * 64, n0 = (swz & 15) * 64;
  ushort_t* As = smem;                            // [2][4096]
  ushort_t* Bs = smem + 8192;                     // [2][4096]

  auto stage = [&](int buf, int kt) {             // 4 gload_lds / thread
#pragma unroll
    for (int q = 0; q < 2; ++q) {
      int lin = (tid + q * 256) * 8;
      int row = lin >> 6;
      int col = ((((lin >> 3) & 7) ^ (row & 7)) << 3);
      gload_lds16(xb + (long)(m0 + row) * 512 + kt + col, &As[buf * 4096 + lin]);
      gload_lds16(Wth + (long)(n0 + row) * 512 + kt + col, &Bs[buf * 4096 + lin]);
    }
  };

  f32x4 acc[2][2] = {};
  auto compute = [&](int b) {
#pragma unroll
    for (int kk = 0; kk < 64; kk += 32) {
      bf16x8 a[2], bb[2];
#pragma unroll
      for (int f = 0; f < 2; ++f) {
        int ra = wm * 32 + f * 16 + r16;
        int rb = wn * 32 + f * 16 + r16;
        a[f]  = *(const bf16x8*)&As[b * 4096 + ra * 64 + ((kk + kg * 8) ^ ((ra & 7) * 8))];
        bb[f] = *(const bf16x8*)&Bs[b * 4096 + rb * 64 + ((kk + kg * 8) ^ ((rb & 7) * 8))];
      }
#pragma unroll
      for (int i = 0; i < 2; ++i)
#pragma unroll
        for (int j = 0; j < 2; ++j)
          acc[i][j] = __builtin_amdgcn_mfma_f32_16x16x32_bf16(a[i], bb[j], acc[i][j], 0, 0, 0);
    }
  };

  stage(0, 0);
  stage(1, 64);
  asm volatile("s_waitcnt vmcnt(4)" ::: "memory");
  __builtin_amdgcn_s_barrier();
  __builtin_amdgcn_sched_barrier(0);

  for (int t = 0; t < 8; ++t) {
    compute(t & 1);
    if (t == 7) break;
    asm volatile("s_waitcnt lgkmcnt(0)" ::: "memory");
    __builtin_amdgcn_sched_barrier(0);
    __builtin_amdgcn_s_barrier();
    if (t + 2 < 8) {
      stage(t & 1, (t + 2) * 64);
      asm volatile("s_waitcnt vmcnt(4)" ::: "memory");
    } else {
      asm volatile("s_waitcnt vmcnt(0)" ::: "memory");
    }
    __builtin_amdgcn_s_barrier();
    __builtin_amdgcn_sched_barrier(0);
  }
  __builtin_amdgcn_sched_barrier(0);

  const float invL = prm[21];
  const float d0 = prm[20];
  const float lam = prm[22];
  float aw[20];
#pragma unroll
  for (int k = 0; k < 20; ++k) aw[k] = prm[k];
#pragma unroll
  for (int i = 0; i < 2; ++i)
#pragma unroll
    for (int j = 0; j < 2; ++j)
#pragma unroll
      for (int r = 0; r < 4; ++r) {
        int row = m0 + wm * 32 + i * 16 + (lane >> 4) * 4 + r;
        int col = n0 + wn * 32 + j * 16 + r16;
        long idx = (long)row * 1024 + col;
        bf16_t xv = __float2bfloat16(acc[i][j][r] * invL);
        xWs[idx] = xv;
        float zop = act_mix(__bfloat162float(xv), aw, lam);
        zB[idx] = __float2bfloat16(zop);
        zaux1[idx] = __float2bfloat16(zop * (1.0f + d0));  // zold = 0
      }
}

// ---------------- main iteration: acc = zaux·G; epilogue -------------------
// Round-12/14 proven config: 64x64 tile, 2-buf counted-vmcnt, 4 blocks/CU,
// A-snapshot from LDS, tail epilogue.
template <bool LAST>
__global__ __launch_bounds__(256, 4) void k_iter(const bf16_t* __restrict__ A,
                                                 const bf16_t* __restrict__ G,
                                                 const bf16_t* __restrict__ xWs,
                                                 bf16_t* __restrict__ zauxN,
                                                 bf16_t* zB, float* zio,
                                                 const float* __restrict__ prm) {
  __shared__ __align__(16) ushort_t As[2][64 * 64], Bs[2][64 * 64];
  const int tid = threadIdx.x, lane = tid & 63, wave = tid >> 6;
  const int wm = wave >> 1, wn = wave & 1;
  const int bid = blockIdx.x;
  const int swz = (bid & 7) * 128 + (bid >> 3);   // XCD swizzle (1024 % 8 == 0)
  const int m0 = (swz >> 4) * 64, n0 = (swz & 15) * 64;
  const int r16 = lane & 15, kg = lane >> 4;

  auto stage = [&](int buf, int kt) {             // 4 gload_lds / thread
#pragma unroll
    for (int q = 0; q < 2; ++q) {
      int lin = (tid + q * 256) * 8;
      int row = lin >> 6;
      int col = ((((lin >> 3) & 7) ^ (row & 7)) << 3);
      gload_lds16(A + (long)(m0 + row) * 1024 + kt + col, &As[buf][lin]);
      gload_lds16(G + (long)(n0 + row) * 1024 + kt + col, &Bs[buf][lin]);
    }
  };

  f32x4 acc[2][2] = {};
  auto compute = [&](int b) {
#pragma unroll
    for (int kk = 0; kk < 64; kk += 32) {
      bf16x8 a[2], bb[2];
#pragma unroll
      for (int f = 0; f < 2; ++f) {
        int ra = wm * 32 + f * 16 + r16;
        int rb = wn * 32 + f * 16 + r16;
        a[f]  = *(const bf16x8*)&As[b][ra * 64 + ((kk + kg * 8) ^ ((ra & 7) * 8))];
        bb[f] = *(const bf16x8*)&Bs[b][rb * 64 + ((kk + kg * 8) ^ ((rb & 7) * 8))];
      }
#pragma unroll
      for (int i = 0; i < 2; ++i)
#pragma unroll
        for (int j = 0; j < 2; ++j)
          acc[i][j] = __builtin_amdgcn_mfma_f32_16x16x32_bf16(a[i], bb[j], acc[i][j], 0, 0, 0);
    }
  };

  const int snap_t = n0 >> 6;                     // K-tile holding cols n0..n0+63
  ushort_t ar[2][2][4];

  stage(0, 0);
  stage(1, 64);
  asm volatile("s_waitcnt vmcnt(4)" ::: "memory");   // tile 0 landed (own)
  __builtin_amdgcn_s_barrier();                      // ...and by all waves
  __builtin_amdgcn_sched_barrier(0);

  for (int t = 0; t < 16; ++t) {
    compute(t & 1);
    if (t == snap_t) {      // A-snapshot from LDS (bit-identical to A[idx])
#pragma unroll
      for (int i = 0; i < 2; ++i)
#pragma unroll
        for (int j = 0; j < 2; ++j)
#pragma unroll
          for (int r = 0; r < 4; ++r) {
            int rl = wm * 32 + i * 16 + (lane >> 4) * 4 + r;
            int cl = wn * 32 + j * 16 + r16;
            ar[i][j][r] = As[t & 1][rl * 64 + (cl ^ ((rl & 7) * 8))];
          }
    }
    if (t == 15) break;
    asm volatile("s_waitcnt lgkmcnt(0)" ::: "memory");
    __builtin_amdgcn_sched_barrier(0);
    __builtin_amdgcn_s_barrier();
    if (t + 2 < 16) {
      stage(t & 1, (t + 2) * 64);
      asm volatile("s_waitcnt vmcnt(4)" ::: "memory"); // tile t+1 done; t+2 in flight
    } else {
      asm volatile("s_waitcnt vmcnt(0)" ::: "memory");
    }
    __builtin_amdgcn_s_barrier();
    __builtin_amdgcn_sched_barrier(0);
  }
  __builtin_amdgcn_sched_barrier(0);

  const float d_i = prm[20];
  const float invL = prm[21];
  const float lam = prm[22];
  float aw[20];
#pragma unroll
  for (int k = 0; k < 20; ++k) aw[k] = prm[k];

  // epilogue: issue remaining operand loads first (ILP), then compute+store
  float xv[2][2][4], zv[2][2][4];
#pragma unroll
  for (int i = 0; i < 2; ++i)
#pragma unroll
    for (int j = 0; j < 2; ++j)
#pragma unroll
      for (int r = 0; r < 4; ++r) {
        int row = m0 + wm * 32 + i * 16 + (lane >> 4) * 4 + r;
        int col = n0 + wn * 32 + j * 16 + r16;
        long idx = (long)row * 1024 + col;
        xv[i][j][r] = __bfloat162float(xWs[idx]);
        if (!LAST) zv[i][j][r] = __bfloat162float(zB[idx]);
      }
#pragma unroll
  for (int i = 0; i < 2; ++i)
#pragma unroll
    for (int j = 0; j < 2; ++j)
#pragma unroll
      for (int r = 0; r < 4; ++r) {
        int row = m0 + wm * 32 + i * 16 + (lane >> 4) * 4 + r;
        int col = n0 + wn * 32 + j * 16 + r16;
        long idx = (long)row * 1024 + col;
        float zg = fmaf(-acc[i][j][r], invL, us2f(ar[i][j][r]) + xv[i][j][r]);
        float zop = act_mix(zg, aw, lam);
        if (LAST) {
          zio[idx] = zop;
        } else {
          zB[idx] = __float2bfloat16(zop);
          zauxN[idx] = __float2bfloat16(fmaf(d_i, zop - zv[i][j][r], zop));
        }
      }
}

// ---------------- orchestration ----------------
extern "C" void kernel_launch(void* const* d_in, const int* in_sizes, int n_in,
                              void* d_out, int out_size, void* d_ws, size_t ws_size,
                              hipStream_t stream) {
  const float* x     = (const float*)d_in[0];
  const float* W     = (const float*)d_in[1];
  const float* alpha = (const float*)d_in[2];
  const float* beta  = (const float*)d_in[3];
  float* zout = (float*)d_out;

  char* ws = (char*)d_ws;
  const size_t MB = 1u << 20;
  float* pb     = (float*)(ws);                  // 8 x 256 f32 partials (8 KB)
  float* numP   = (float*)(ws + 10 * 1024);
  float* denP   = (float*)(ws + 11 * 1024);
  float* params = (float*)(ws + 12 * 1024);
  int*   flags  = (int*)(ws + 14 * 1024);        // 256 ints
  int*   gen    = (int*)(ws + 15 * 1024);        // 1 int
  const size_t HDR = 32768;
  float*  A0f  = (float*)(ws + HDR);                 // 1 MB
  bf16_t* H0   = (bf16_t*)(ws + HDR + 2 * MB);       // 0.5 MB
  bf16_t* L0   = (bf16_t*)(ws + HDR + 2 * MB + 512 * 1024);
  bf16_t* H1   = (bf16_t*)(ws + HDR + 3 * MB);
  bf16_t* L1   = (bf16_t*)(ws + HDR + 3 * MB + 512 * 1024);
  bf16_t* Whi  = (bf16_t*)(ws + HDR + 4 * MB);       // 1 MB
  bf16_t* Wlo  = (bf16_t*)(ws + HDR + 5 * MB);       // 1 MB
  bf16_t* Wth  = (bf16_t*)(ws + HDR + 6 * MB);       // 1 MB
  bf16_t* Wtl  = (bf16_t*)(ws + HDR + 7 * MB);       // 1 MB
  bf16_t* Gm   = (bf16_t*)(ws + HDR + 8 * MB);       // 2 MB
  bf16_t* xb   = (bf16_t*)(ws + HDR + 10 * MB);      // 4 MB
  bf16_t* xWs  = (bf16_t*)(ws + HDR + 18 * MB);      // 8 MB (bf16, pre-scaled by invL)
  bf16_t* zx0  = (bf16_t*)(ws + HDR + 26 * MB);      // 8 MB (zaux ping)
  bf16_t* zx1  = (bf16_t*)(ws + HDR + 34 * MB);      // 8 MB (zaux pong)
  bf16_t* zB   = (bf16_t*)(ws + HDR + 42 * MB);      // 8 MB (z storage)

  // zero the grid-barrier state (flags + gen); capture-safe, replayed each run
  hipMemsetAsync(ws + 14 * 1024, 0, 2048, stream);

  k_prep<<<10240, 256, 0, stream>>>(W, x, Whi, Wlo, Wth, Wtl, xb);

  // fused L-chain: A0=W*W^T, 7 squarings, DOT, setup — ONE launch
  k_Lchain<<<256, 256, 0, stream>>>(Whi, Wlo, H0, L0, H1, L1, A0f, pb,
                                    numP, denP, alpha, beta, params,
                                    flags, gen);

  // merged G + (xWs + iter0): one launch, 2048 blocks
  k_gx<<<2048, 256, 0, stream>>>(xb, Wth, Wtl, params, Gm, xWs, zB, zx1);

  // iters 1..9: zaux ping-pong; iter i reads zx[i&1], writes zx[(i+1)&1]
  bf16_t* zx[2] = {zx0, zx1};
  for (int i = 1; i < 9; ++i)
    k_iter<false><<<1024, 256, 0, stream>>>(zx[i & 1], Gm, xWs, zx[(i + 1) & 1],
                                            zB, zout, params + i * 32);
  k_iter<true><<<1024, 256, 0, stream>>>(zx[9 & 1], Gm, xWs, zx0 /*unused*/,
                                         zB, zout, params + 9 * 32);
}

// Round 16
// 339.815 us; speedup vs baseline: 2.5753x; 2.5753x over previous
//
#include <hip/hip_runtime.h>
#include <hip/hip_bf16.h>

#define DI __device__ __forceinline__

typedef float f32x4 __attribute__((ext_vector_type(4)));
typedef __bf16 bf16x8 __attribute__((ext_vector_type(8)));
using bf16_t = __hip_bfloat16;
using ushort_t = unsigned short;

// ---------------- async global->LDS (16B per lane) ----------------
DI void gload_lds16(const void* g, void* l) {
  __builtin_amdgcn_global_load_lds(
      (const __attribute__((address_space(1))) void*)g,
      (__attribute__((address_space(3))) void*)l, 16, 0, 0);
}

DI float rcpf(float x) { return __builtin_amdgcn_rcpf(x); }

DI float us2f(ushort_t u) {
  bf16_t h;
  *reinterpret_cast<ushort_t*>(&h) = u;
  return __bfloat162float(h);
}

// ---------------- 20-way weighted activation mixture ----------------
DI float act_mix(float x, const float* aw, float lam) {
  const float ax  = fabsf(x);
  const float en  = __expf(-ax);        // e^{-|x|} in (0,1]
  const float en2 = en * en;            // e^{-2|x|}
  const float i1  = rcpf(1.0f + en);
  const float sig = (x >= 0.0f) ? i1 : en * i1;            // sigmoid
  const float th  = copysignf((1.0f - en2) * rcpf(1.0f + en2), x); // tanh
  const float l1p = __logf(1.0f + en);
  const float sp  = fmaxf(x, 0.0f) + l1p;                  // softplus
  const float lsg = fminf(x, 0.0f) - l1p;                  // logsigmoid
  const float q   = ((x >= 0.0f) ? en2 : 1.0f) * (i1 * i1);// e^{-2*softplus}
  const float mish = x * (1.0f - q) * rcpf(1.0f + q);
  // gelu exact via A&S 7.1.26 erf approx (|err|<=1.5e-7)
  const float u  = 0.7071067811865476f * x;
  const float au = fabsf(u);
  const float t  = rcpf(1.0f + 0.3275911f * au);
  float poly = fmaf(t, 1.061405429f, -1.453152027f);
  poly = fmaf(t, poly, 1.421413741f);
  poly = fmaf(t, poly, -0.284496736f);
  poly = fmaf(t, poly, 0.254829592f);
  poly *= t;
  const float erfa = 1.0f - poly * __expf(-u * u);
  const float gelu = 0.5f * x * (1.0f + copysignf(erfa, x));
  const float em1  = en - 1.0f;                            // e^x-1 for x<=0
  const float elu  = (x > 0.0f) ? x : em1;
  const float selu = (x > 0.0f) ? 1.0507009873554805f * x : 1.7580993408473766f * em1;
  const float relu = fmaxf(x, 0.0f);
  const float t6   = fminf(fmaxf(x + 3.0f, 0.0f), 6.0f) * 0.16666666666666666f;
  const float ssh  = (x > lam) ? (x - lam) : ((x < -lam) ? (x + lam) : 0.0f);
  const float hsh  = (ax > lam) ? x : 0.0f;
  const float htan = fminf(fmaxf(x, -1.0f), 1.0f);
  const float lky  = (x >= 0.0f) ? x : 0.01f * x;
  const float ssn  = x * rcpf(1.0f + ax);
  float r = aw[0] * ssh;
  r = fmaf(aw[1],  relu,   r);
  r = fmaf(aw[2],  x,      r);
  r = fmaf(aw[3],  gelu,   r);
  r = fmaf(aw[4],  elu,    r);
  r = fmaf(aw[5],  hsh,    r);
  r = fmaf(aw[6],  htan,   r);
  r = fmaf(aw[7],  x * t6, r);
  r = fmaf(aw[8],  selu,   r);
  r = fmaf(aw[9],  elu,    r);   // celu(alpha=1) == elu
  r = fmaf(aw[10], lky,    r);
  r = fmaf(aw[11], lsg,    r);
  r = fmaf(aw[12], x - th, r);
  r = fmaf(aw[13], ssn,    r);
  r = fmaf(aw[14], sp,     r);
  r = fmaf(aw[15], th,     r);
  r = fmaf(aw[16], sig,    r);
  r = fmaf(aw[17], t6,     r);
  r = fmaf(aw[18], x * sig, r);
  r = fmaf(aw[19], mish,   r);
  return r;
}

// ---------------- fused prep: hi/lo splits of W (+W^T); x -> bf16 ----------
__global__ void k_prep(const float* __restrict__ W, const float* __restrict__ x,
                       bf16_t* __restrict__ Whi, bf16_t* __restrict__ Wlo,
                       bf16_t* __restrict__ Wth, bf16_t* __restrict__ Wtl,
                       bf16_t* __restrict__ xb) {
  int i = blockIdx.x * 256 + threadIdx.x;
  if (i < 512 * 1024) {
    float w = W[i];
    bf16_t h = __float2bfloat16(w);
    bf16_t l = __float2bfloat16(w - __bfloat162float(h));
    Whi[i] = h; Wlo[i] = l;
    int n = i >> 10, hc = i & 1023;
    Wth[hc * 512 + n] = h; Wtl[hc * 512 + n] = l;
  }
  int j = i - 512 * 1024;
  if (j >= 0 && j < 4096 * 512) xb[j] = __float2bfloat16(x[j]);
}

// ---------------- L pipeline: MFMA hi/lo squaring ----------------
// FIRST+7 squarings + DOT-squaring = B = A_hat^256; Rayleigh error
// ~ gap(0.016) * (l2/l1)^256 ~ 3e-4 relative -> sub-bf16-quantum (validated
// rounds 11/12/14: absmax unchanged at 0.015625).
// Counted-vmcnt pipeline (round 14). Separate launches per squaring are
// KEPT deliberately: round 15 measured a software device-scope grid barrier
// at ~60us/barrier (non-coherent per-XCD L2 -> memory-side spin convoy) vs
// ~5us/kernel boundary; round 13's cooperative launch was silently rejected.
// Launch boundaries ARE the cheap grid sync on MI355X.
template <int KDIM, bool FIRST, bool DOT>
__global__ __launch_bounds__(256) void k_sqm(
    const bf16_t* __restrict__ Xhi, const bf16_t* __restrict__ Xlo,
    bf16_t* __restrict__ Chi, bf16_t* __restrict__ Clo,
    float* __restrict__ Cf,                 // out if FIRST, in (A0) if DOT
    const float* __restrict__ pin, float* __restrict__ pout,
    float* __restrict__ numP, float* __restrict__ denP) {
  __shared__ __align__(16) ushort_t Ah[2][32 * 64], Al[2][32 * 64],
                                    Bh[2][32 * 64], Bl[2][32 * 64];
  __shared__ float red[4], redd[4];
  const int tid = threadIdx.x, lane = tid & 63, wave = tid >> 6;
  const int wm = wave >> 1, wn = wave & 1;
  const int i0 = blockIdx.x * 32, j0 = blockIdx.y * 32;
  const int bid = blockIdx.y * gridDim.x + blockIdx.x;
  const int r16 = lane & 15, kg = lane >> 4;

  float s = 1.0f;
  if constexpr (!FIRST) {
    float v = pin[tid];
    for (int off = 32; off; off >>= 1) v += __shfl_down(v, off, 64);
    if ((tid & 63) == 0) red[tid >> 6] = v;
    __syncthreads();
    s = 1.0f / (red[0] + red[1] + red[2] + red[3]);
    __syncthreads();
  }

  const int row = tid >> 3;
  const int srcc = (((tid & 7) ^ (row & 7)) << 3);
  const long abase = (long)(i0 + row) * KDIM + srcc;
  const long bbase = (long)(j0 + row) * KDIM + srcc;
  const int ldst = tid * 8;

  auto stage = [&](int buf, int kt) {             // 4 gload_lds / thread
    gload_lds16(Xhi + abase + kt, &Ah[buf][ldst]);
    gload_lds16(Xlo + abase + kt, &Al[buf][ldst]);
    gload_lds16(Xhi + bbase + kt, &Bh[buf][ldst]);
    gload_lds16(Xlo + bbase + kt, &Bl[buf][ldst]);
  };

  f32x4 acc = {};
  constexpr int NT = KDIM / 64;

  auto compute = [&](int b) {
    const int ra = wm * 16 + r16, rb = wn * 16 + r16;
#pragma unroll
    for (int kk = 0; kk < 64; kk += 32) {
      int oa = ra * 64 + ((kk + kg * 8) ^ ((ra & 7) * 8));
      int ob = rb * 64 + ((kk + kg * 8) ^ ((rb & 7) * 8));
      bf16x8 ah = *(const bf16x8*)&Ah[b][oa];
      bf16x8 al = *(const bf16x8*)&Al[b][oa];
      bf16x8 bh = *(const bf16x8*)&Bh[b][ob];
      bf16x8 bl = *(const bf16x8*)&Bl[b][ob];
      acc = __builtin_amdgcn_mfma_f32_16x16x32_bf16(ah, bh, acc, 0, 0, 0);
      acc = __builtin_amdgcn_mfma_f32_16x16x32_bf16(ah, bl, acc, 0, 0, 0);
      acc = __builtin_amdgcn_mfma_f32_16x16x32_bf16(al, bh, acc, 0, 0, 0);
    }
  };

  stage(0, 0);
  stage(1, 64);
  asm volatile("s_waitcnt vmcnt(4)" ::: "memory");   // tile 0 landed (own)
  __builtin_amdgcn_s_barrier();                      // ...and by all waves
  __builtin_amdgcn_sched_barrier(0);

  for (int t = 0; t < NT; ++t) {
    compute(t & 1);
    if (t == NT - 1) break;
    asm volatile("s_waitcnt lgkmcnt(0)" ::: "memory");
    __builtin_amdgcn_sched_barrier(0);
    __builtin_amdgcn_s_barrier();
    if (t + 2 < NT) {
      stage(t & 1, (t + 2) * 64);
      asm volatile("s_waitcnt vmcnt(4)" ::: "memory"); // tile t+1 done; t+2 in flight
    } else {
      asm volatile("s_waitcnt vmcnt(0)" ::: "memory");
    }
    __builtin_amdgcn_s_barrier();
    __builtin_amdgcn_sched_barrier(0);
  }
  __builtin_amdgcn_sched_barrier(0);

  float fro = 0.0f, dvp = 0.0f;
#pragma unroll
  for (int r = 0; r < 4; ++r) {
    float c = acc[r] * s;
    int orow = i0 + wm * 16 + (lane >> 4) * 4 + r;
    int ocol = j0 + wn * 16 + r16;
    int idx = orow * 512 + ocol;
    if constexpr (DOT) {
      fro = fmaf(Cf[idx], c, fro);        // tr(A0 * C) partial
      if (orow == ocol) dvp += c;         // tr(C) partial
    } else {
      bf16_t h = __float2bfloat16(c);
      Chi[idx] = h;
      Clo[idx] = __float2bfloat16(c - __bfloat162float(h));
      if constexpr (FIRST) Cf[idx] = c;
      fro = fmaf(c, c, fro);
    }
  }
  for (int off = 32; off; off >>= 1) {
    fro += __shfl_down(fro, off, 64);
    if constexpr (DOT) dvp += __shfl_down(dvp, off, 64);
  }
  if ((tid & 63) == 0) { red[tid >> 6] = fro; if constexpr (DOT) redd[tid >> 6] = dvp; }
  __syncthreads();
  if (tid == 0) {
    if constexpr (DOT) {
      numP[bid] = red[0] + red[1] + red[2] + red[3];
      denP[bid] = redd[0] + redd[1] + redd[2] + redd[3];
    } else {
      pout[bid] = red[0] + red[1] + red[2] + red[3];
    }
  }
}

__global__ __launch_bounds__(256) void k_setup(const float* __restrict__ alpha,
                                               const float* __restrict__ beta,
                                               const float* __restrict__ numP,
                                               const float* __restrict__ denP,
                                               float* __restrict__ params) {
  __shared__ float redn[4], redd[4];
  __shared__ float Lsh;
  const int tid = threadIdx.x;
  float nv = numP[tid], dv = denP[tid];
  for (int off = 32; off; off >>= 1) {
    nv += __shfl_down(nv, off, 64);
    dv += __shfl_down(dv, off, 64);
  }
  if ((tid & 63) == 0) { redn[tid >> 6] = nv; redd[tid >> 6] = dv; }
  __syncthreads();
  if (tid == 0)
    Lsh = (redn[0] + redn[1] + redn[2] + redn[3]) /
          (redd[0] + redd[1] + redd[2] + redd[3]);
  __syncthreads();
  const int t = tid;
  if (t >= 10) return;
  float L = Lsh;
  float invL = 1.0f / L;
  float lam = 0.001f * invL;
  const float* a = alpha + t * 20;
  float mx = a[0];
  for (int k = 1; k < 20; ++k) mx = fmaxf(mx, a[k]);
  float e[20], ssum = 0.0f;
  for (int k = 0; k < 20; ++k) { e[k] = expf(a[k] - mx); ssum += e[k]; }
  float inv = 1.0f / ssum;
  float* P = params + t * 32;
  for (int k = 0; k < 20; ++k) P[k] = e[k] * inv;
  float b0 = beta[t * 2], b1 = beta[t * 2 + 1];
  float bm = fmaxf(b0, b1);
  float eb0 = expf(b0 - bm), eb1 = expf(b1 - bm);
  float bw0 = eb0 / (eb0 + eb1);
  P[20] = ((float)(t + 1) / (float)(t + 4)) * bw0;  // c_{i+1} * bw0_i
  P[21] = invL;
  P[22] = lam;
  P[23] = L;
}

// ---------------- merged: G = W^T W  AND  xWs + fused iter 0 ----------------
__global__ __launch_bounds__(256, 4) void k_gx(
    const bf16_t* __restrict__ xb, const bf16_t* __restrict__ Wth,
    const bf16_t* __restrict__ Wtl, const float* __restrict__ prm,
    bf16_t* __restrict__ Gm, bf16_t* __restrict__ xWs,
    bf16_t* __restrict__ zB, bf16_t* __restrict__ zaux1) {
  __shared__ __align__(16) ushort_t smem[16384];   // 32 KB
  const int tid = threadIdx.x, lane = tid & 63, wave = tid >> 6;
  const int wm = wave >> 1, wn = wave & 1;
  const int r16 = lane & 15, kg = lane >> 4;

  if ((int)blockIdx.x >= 1024) {
    // ---------- G part: 1024 blocks of 32x32, hi/lo 3-term ----------
    const int gb = blockIdx.x - 1024;
    const int i0 = (gb & 31) * 32, j0 = (gb >> 5) * 32;
    ushort_t* Ah = smem;            // [2][2048] each
    ushort_t* Al = smem + 4096;
    ushort_t* Bh = smem + 8192;
    ushort_t* Bl = smem + 12288;
    const int row = tid >> 3;
    const int srcc = (((tid & 7) ^ (row & 7)) << 3);
    const long abase = (long)(i0 + row) * 512 + srcc;
    const long bbase = (long)(j0 + row) * 512 + srcc;
    const int ldst = tid * 8;
    auto stg = [&](int buf, int kt) {
      gload_lds16(Wth + abase + kt, &Ah[buf * 2048 + ldst]);
      gload_lds16(Wtl + abase + kt, &Al[buf * 2048 + ldst]);
      gload_lds16(Wth + bbase + kt, &Bh[buf * 2048 + ldst]);
      gload_lds16(Wtl + bbase + kt, &Bl[buf * 2048 + ldst]);
    };
    f32x4 acc = {};
    stg(0, 0);
    __syncthreads();
    for (int t = 0; t < 8; ++t) {
      if (t + 1 < 8) stg((t + 1) & 1, (t + 1) * 64);
      const int b = t & 1;
      const int ra = wm * 16 + r16, rb = wn * 16 + r16;
#pragma unroll
      for (int kk = 0; kk < 64; kk += 32) {
        int oa = b * 2048 + ra * 64 + ((kk + kg * 8) ^ ((ra & 7) * 8));
        int ob = b * 2048 + rb * 64 + ((kk + kg * 8) ^ ((rb & 7) * 8));
        bf16x8 ah = *(const bf16x8*)&Ah[oa];
        bf16x8 al = *(const bf16x8*)&Al[oa];
        bf16x8 bh = *(const bf16x8*)&Bh[ob];
        bf16x8 bl = *(const bf16x8*)&Bl[ob];
        acc = __builtin_amdgcn_mfma_f32_16x16x32_bf16(ah, bh, acc, 0, 0, 0);
        acc = __builtin_amdgcn_mfma_f32_16x16x32_bf16(ah, bl, acc, 0, 0, 0);
        acc = __builtin_amdgcn_mfma_f32_16x16x32_bf16(al, bh, acc, 0, 0, 0);
      }
      __syncthreads();
    }
#pragma unroll
    for (int r = 0; r < 4; ++r) {
      int orow = i0 + wm * 16 + (lane >> 4) * 4 + r;
      int ocol = j0 + wn * 16 + r16;
      Gm[orow * 1024 + ocol] = __float2bfloat16(acc[r]);
    }
    return;
  }

  // ---------- xw part: 1024 blocks, counted-vmcnt pipeline ----------
  const int bid = blockIdx.x;
  const int swz = (bid & 7) * 128 + (bid >> 3);   // XCD swizzle
  const int m0 = (swz >> 4) * 64, n0 = (swz & 15) * 64;
  ushort_t* As = smem;                            // [2][4096]
  ushort_t* Bs = smem + 8192;                     // [2][4096]

  auto stage = [&](int buf, int kt) {             // 4 gload_lds / thread
#pragma unroll
    for (int q = 0; q < 2; ++q) {
      int lin = (tid + q * 256) * 8;
      int row = lin >> 6;
      int col = ((((lin >> 3) & 7) ^ (row & 7)) << 3);
      gload_lds16(xb + (long)(m0 + row) * 512 + kt + col, &As[buf * 4096 + lin]);
      gload_lds16(Wth + (long)(n0 + row) * 512 + kt + col, &Bs[buf * 4096 + lin]);
    }
  };

  f32x4 acc[2][2] = {};
  auto compute = [&](int b) {
#pragma unroll
    for (int kk = 0; kk < 64; kk += 32) {
      bf16x8 a[2], bb[2];
#pragma unroll
      for (int f = 0; f < 2; ++f) {
        int ra = wm * 32 + f * 16 + r16;
        int rb = wn * 32 + f * 16 + r16;
        a[f]  = *(const bf16x8*)&As[b * 4096 + ra * 64 + ((kk + kg * 8) ^ ((ra & 7) * 8))];
        bb[f] = *(const bf16x8*)&Bs[b * 4096 + rb * 64 + ((kk + kg * 8) ^ ((rb & 7) * 8))];
      }
#pragma unroll
      for (int i = 0; i < 2; ++i)
#pragma unroll
        for (int j = 0; j < 2; ++j)
          acc[i][j] = __builtin_amdgcn_mfma_f32_16x16x32_bf16(a[i], bb[j], acc[i][j], 0, 0, 0);
    }
  };

  stage(0, 0);
  stage(1, 64);
  asm volatile("s_waitcnt vmcnt(4)" ::: "memory");
  __builtin_amdgcn_s_barrier();
  __builtin_amdgcn_sched_barrier(0);

  for (int t = 0; t < 8; ++t) {
    compute(t & 1);
    if (t == 7) break;
    asm volatile("s_waitcnt lgkmcnt(0)" ::: "memory");
    __builtin_amdgcn_sched_barrier(0);
    __builtin_amdgcn_s_barrier();
    if (t + 2 < 8) {
      stage(t & 1, (t + 2) * 64);
      asm volatile("s_waitcnt vmcnt(4)" ::: "memory");
    } else {
      asm volatile("s_waitcnt vmcnt(0)" ::: "memory");
    }
    __builtin_amdgcn_s_barrier();
    __builtin_amdgcn_sched_barrier(0);
  }
  __builtin_amdgcn_sched_barrier(0);

  const float invL = prm[21];
  const float d0 = prm[20];
  const float lam = prm[22];
  float aw[20];
#pragma unroll
  for (int k = 0; k < 20; ++k) aw[k] = prm[k];
#pragma unroll
  for (int i = 0; i < 2; ++i)
#pragma unroll
    for (int j = 0; j < 2; ++j)
#pragma unroll
      for (int r = 0; r < 4; ++r) {
        int row = m0 + wm * 32 + i * 16 + (lane >> 4) * 4 + r;
        int col = n0 + wn * 32 + j * 16 + r16;
        long idx = (long)row * 1024 + col;
        bf16_t xv = __float2bfloat16(acc[i][j][r] * invL);
        xWs[idx] = xv;
        float zop = act_mix(__bfloat162float(xv), aw, lam);
        zB[idx] = __float2bfloat16(zop);
        zaux1[idx] = __float2bfloat16(zop * (1.0f + d0));  // zold = 0
      }
}

// ---------------- main iteration: acc = zaux·G; epilogue -------------------
// Round-12/14 proven config: 64x64 tile, 2-buf counted-vmcnt, 4 blocks/CU,
// A-snapshot from LDS, tail epilogue.
template <bool LAST>
__global__ __launch_bounds__(256, 4) void k_iter(const bf16_t* __restrict__ A,
                                                 const bf16_t* __restrict__ G,
                                                 const bf16_t* __restrict__ xWs,
                                                 bf16_t* __restrict__ zauxN,
                                                 bf16_t* zB, float* zio,
                                                 const float* __restrict__ prm) {
  __shared__ __align__(16) ushort_t As[2][64 * 64], Bs[2][64 * 64];
  const int tid = threadIdx.x, lane = tid & 63, wave = tid >> 6;
  const int wm = wave >> 1, wn = wave & 1;
  const int bid = blockIdx.x;
  const int swz = (bid & 7) * 128 + (bid >> 3);   // XCD swizzle (1024 % 8 == 0)
  const int m0 = (swz >> 4) * 64, n0 = (swz & 15) * 64;
  const int r16 = lane & 15, kg = lane >> 4;

  auto stage = [&](int buf, int kt) {             // 4 gload_lds / thread
#pragma unroll
    for (int q = 0; q < 2; ++q) {
      int lin = (tid + q * 256) * 8;
      int row = lin >> 6;
      int col = ((((lin >> 3) & 7) ^ (row & 7)) << 3);
      gload_lds16(A + (long)(m0 + row) * 1024 + kt + col, &As[buf][lin]);
      gload_lds16(G + (long)(n0 + row) * 1024 + kt + col, &Bs[buf][lin]);
    }
  };

  f32x4 acc[2][2] = {};
  auto compute = [&](int b) {
#pragma unroll
    for (int kk = 0; kk < 64; kk += 32) {
      bf16x8 a[2], bb[2];
#pragma unroll
      for (int f = 0; f < 2; ++f) {
        int ra = wm * 32 + f * 16 + r16;
        int rb = wn * 32 + f * 16 + r16;
        a[f]  = *(const bf16x8*)&As[b][ra * 64 + ((kk + kg * 8) ^ ((ra & 7) * 8))];
        bb[f] = *(const bf16x8*)&Bs[b][rb * 64 + ((kk + kg * 8) ^ ((rb & 7) * 8))];
      }
#pragma unroll
      for (int i = 0; i < 2; ++i)
#pragma unroll
        for (int j = 0; j < 2; ++j)
          acc[i][j] = __builtin_amdgcn_mfma_f32_16x16x32_bf16(a[i], bb[j], acc[i][j], 0, 0, 0);
    }
  };

  const int snap_t = n0 >> 6;                     // K-tile holding cols n0..n0+63
  ushort_t ar[2][2][4];

  stage(0, 0);
  stage(1, 64);
  asm volatile("s_waitcnt vmcnt(4)" ::: "memory");   // tile 0 landed (own)
  __builtin_amdgcn_s_barrier();                      // ...and by all waves
  __builtin_amdgcn_sched_barrier(0);

  for (int t = 0; t < 16; ++t) {
    compute(t & 1);
    if (t == snap_t) {      // A-snapshot from LDS (bit-identical to A[idx])
#pragma unroll
      for (int i = 0; i < 2; ++i)
#pragma unroll
        for (int j = 0; j < 2; ++j)
#pragma unroll
          for (int r = 0; r < 4; ++r) {
            int rl = wm * 32 + i * 16 + (lane >> 4) * 4 + r;
            int cl = wn * 32 + j * 16 + r16;
            ar[i][j][r] = As[t & 1][rl * 64 + (cl ^ ((rl & 7) * 8))];
          }
    }
    if (t == 15) break;
    asm volatile("s_waitcnt lgkmcnt(0)" ::: "memory");
    __builtin_amdgcn_sched_barrier(0);
    __builtin_amdgcn_s_barrier();
    if (t + 2 < 16) {
      stage(t & 1, (t + 2) * 64);
      asm volatile("s_waitcnt vmcnt(4)" ::: "memory"); // tile t+1 done; t+2 in flight
    } else {
      asm volatile("s_waitcnt vmcnt(0)" ::: "memory");
    }
    __builtin_amdgcn_s_barrier();
    __builtin_amdgcn_sched_barrier(0);
  }
  __builtin_amdgcn_sched_barrier(0);

  const float d_i = prm[20];
  const float invL = prm[21];
  const float lam = prm[22];
  float aw[20];
#pragma unroll
  for (int k = 0; k < 20; ++k) aw[k] = prm[k];

  // epilogue: issue remaining operand loads first (ILP), then compute+store
  float xv[2][2][4], zv[2][2][4];
#pragma unroll
  for (int i = 0; i < 2; ++i)
#pragma unroll
    for (int j = 0; j < 2; ++j)
#pragma unroll
      for (int r = 0; r < 4; ++r) {
        int row = m0 + wm * 32 + i * 16 + (lane >> 4) * 4 + r;
        int col = n0 + wn * 32 + j * 16 + r16;
        long idx = (long)row * 1024 + col;
        xv[i][j][r] = __bfloat162float(xWs[idx]);
        if (!LAST) zv[i][j][r] = __bfloat162float(zB[idx]);
      }
#pragma unroll
  for (int i = 0; i < 2; ++i)
#pragma unroll
    for (int j = 0; j < 2; ++j)
#pragma unroll
      for (int r = 0; r < 4; ++r) {
        int row = m0 + wm * 32 + i * 16 + (lane >> 4) * 4 + r;
        int col = n0 + wn * 32 + j * 16 + r16;
        long idx = (long)row * 1024 + col;
        float zg = fmaf(-acc[i][j][r], invL, us2f(ar[i][j][r]) + xv[i][j][r]);
        float zop = act_mix(zg, aw, lam);
        if (LAST) {
          zio[idx] = zop;
        } else {
          zB[idx] = __float2bfloat16(zop);
          zauxN[idx] = __float2bfloat16(fmaf(d_i, zop - zv[i][j][r], zop));
        }
      }
}

// ---------------- orchestration ----------------
extern "C" void kernel_launch(void* const* d_in, const int* in_sizes, int n_in,
                              void* d_out, int out_size, void* d_ws, size_t ws_size,
                              hipStream_t stream) {
  const float* x     = (const float*)d_in[0];
  const float* W     = (const float*)d_in[1];
  const float* alpha = (const float*)d_in[2];
  const float* beta  = (const float*)d_in[3];
  float* zout = (float*)d_out;

  char* ws = (char*)d_ws;
  const size_t MB = 1u << 20;
  float* pb[9];
  for (int k = 0; k < 9; ++k) pb[k] = (float*)(ws + (size_t)k * 1024);
  float* numP   = (float*)(ws + 10 * 1024);
  float* denP   = (float*)(ws + 11 * 1024);
  float* params = (float*)(ws + 12 * 1024);
  const size_t HDR = 32768;
  float*  A0f  = (float*)(ws + HDR);                 // 1 MB
  bf16_t* H0   = (bf16_t*)(ws + HDR + 2 * MB);       // 0.5 MB
  bf16_t* L0   = (bf16_t*)(ws + HDR + 2 * MB + 512 * 1024);
  bf16_t* H1   = (bf16_t*)(ws + HDR + 3 * MB);
  bf16_t* L1   = (bf16_t*)(ws + HDR + 3 * MB + 512 * 1024);
  bf16_t* Whi  = (bf16_t*)(ws + HDR + 4 * MB);       // 1 MB
  bf16_t* Wlo  = (bf16_t*)(ws + HDR + 5 * MB);       // 1 MB
  bf16_t* Wth  = (bf16_t*)(ws + HDR + 6 * MB);       // 1 MB
  bf16_t* Wtl  = (bf16_t*)(ws + HDR + 7 * MB);       // 1 MB
  bf16_t* Gm   = (bf16_t*)(ws + HDR + 8 * MB);       // 2 MB
  bf16_t* xb   = (bf16_t*)(ws + HDR + 10 * MB);      // 4 MB
  bf16_t* xWs  = (bf16_t*)(ws + HDR + 18 * MB);      // 8 MB (bf16, pre-scaled by invL)
  bf16_t* zx0  = (bf16_t*)(ws + HDR + 26 * MB);      // 8 MB (zaux ping)
  bf16_t* zx1  = (bf16_t*)(ws + HDR + 34 * MB);      // 8 MB (zaux pong)
  bf16_t* zB   = (bf16_t*)(ws + HDR + 42 * MB);      // 8 MB (z storage)

  k_prep<<<10240, 256, 0, stream>>>(W, x, Whi, Wlo, Wth, Wtl, xb);

  // L: A0 = W*W^T (hi/lo), 7 normalized squarings, then DOT-squaring
  k_sqm<1024, true, false><<<dim3(16, 16), 256, 0, stream>>>(
      Whi, Wlo, H0, L0, A0f, nullptr, pb[0], nullptr, nullptr);
  bf16_t* Hs[2] = {H0, H1};
  bf16_t* Ls[2] = {L0, L1};
  int pp = 0;
  for (int k = 0; k < 7; ++k) {
    k_sqm<512, false, false><<<dim3(16, 16), 256, 0, stream>>>(
        Hs[pp], Ls[pp], Hs[pp ^ 1], Ls[pp ^ 1], nullptr, pb[k], pb[k + 1],
        nullptr, nullptr);
    pp ^= 1;
  }
  k_sqm<512, false, true><<<dim3(16, 16), 256, 0, stream>>>(
      Hs[pp], Ls[pp], nullptr, nullptr, A0f, pb[7], nullptr, numP, denP);
  k_setup<<<1, 256, 0, stream>>>(alpha, beta, numP, denP, params);

  // merged G + (xWs + iter0): one launch, 2048 blocks
  k_gx<<<2048, 256, 0, stream>>>(xb, Wth, Wtl, params, Gm, xWs, zB, zx1);

  // iters 1..9: zaux ping-pong; iter i reads zx[i&1], writes zx[(i+1)&1]
  bf16_t* zx[2] = {zx0, zx1};
  for (int i = 1; i < 9; ++i)
    k_iter<false><<<1024, 256, 0, stream>>>(zx[i & 1], Gm, xWs, zx[(i + 1) & 1],
                                            zB, zout, params + i * 32);
  k_iter<true><<<1024, 256, 0, stream>>>(zx[9 & 1], Gm, xWs, zx0 /*unused*/,
                                         zB, zout, params + 9 * 32);
}